// Round 12
// baseline (627.289 us; speedup 1.0000x reference)
//
#include <hip/hip_runtime.h>

typedef unsigned short u16;
typedef unsigned int u32;
typedef short short8 __attribute__((ext_vector_type(8)));
typedef float f32x4 __attribute__((ext_vector_type(4)));
typedef __bf16 bf16x8 __attribute__((ext_vector_type(8)));
typedef unsigned int u32x4 __attribute__((ext_vector_type(4)));

#define SCALE_QK 0.17677669529663687f  // 1/sqrt(32)

__device__ __forceinline__ u16 f2b(float f) {
    unsigned int u = __builtin_bit_cast(unsigned int, f);
    u += 0x7fffu + ((u >> 16) & 1u);
    return (u16)(u >> 16);
}

__device__ __forceinline__ u32 pack2(float lo, float hi) {
    return ((u32)f2b(hi) << 16) | (u32)f2b(lo);
}

__device__ __forceinline__ f32x4 mfma16(short8 a, short8 b, f32x4 c) {
    return __builtin_amdgcn_mfma_f32_16x16x32_bf16(
        __builtin_bit_cast(bf16x8, a), __builtin_bit_cast(bf16x8, b), c, 0, 0, 0);
}

__device__ __forceinline__ void gload_lds16(const u16* g, u16* l) {
    __builtin_amdgcn_global_load_lds(
        (const __attribute__((address_space(1))) unsigned int*)g,
        (__attribute__((address_space(3))) unsigned int*)l, 16, 0, 0);
}

// bijective XCD-chunked block-id swizzle (m204)
__device__ __forceinline__ int xcd_swizzle(int bid, int nwg) {
    int qd = nwg >> 3, rm = nwg & 7;
    int xcd = bid & 7, lo = bid >> 3;
    return (xcd < rm ? xcd * (qd + 1) : rm * (qd + 1) + (xcd - rm) * qd) + lo;
}

// ---------------- fp32 -> bf16 convert ----------------
__global__ void cvt_kernel(const float4* __restrict__ in, ushort4* __restrict__ out, int n4) {
    int stride = gridDim.x * blockDim.x;
    for (int i = blockIdx.x * blockDim.x + threadIdx.x; i < n4; i += stride) {
        float4 v = in[i];
        ushort4 o;
        o.x = f2b(v.x); o.y = f2b(v.y); o.z = f2b(v.z); o.w = f2b(v.w);
        out[i] = o;
    }
}

// ---------------- bias matrix expand: bm[h][i][j] = ab[h][idx[i][j]] ----------------
// (idx is symmetric -> bm[h] is symmetric; attn reads bm[k][q] relying on this)
__global__ void biasmat_kernel(const float* __restrict__ ab, const int* __restrict__ idxs,
                               float* __restrict__ bm) {
    int total = 8 * 196 * 196;
    int stride = gridDim.x * blockDim.x;
    for (int i = blockIdx.x * blockDim.x + threadIdx.x; i < total; i += stride) {
        int h = i / (196 * 196);
        int ij = i - h * (196 * 196);
        bm[i] = ab[h * 196 + idxs[ij]];
    }
}

// ---------------- bf16 GEMM: C = A(M x K) * Bw(N x K)^T + bias ----------------
// 128x128 tile, 4 waves (64x64 each), BK=32, THREE LDS buffers with 2-deep
// counted-vmcnt prefetch (stage t+2 during compute t; vmcnt(8) retires tile t).
// Bank swizzle: slot ^= (row>>1)&3 -> balanced bank quads (conflict-free, r6 PMC).
// EPI==0: route outputs to q/k/v (qkv, chunk-local).  EPI==1: fp32 out (proj).
template <int KDIM, int NTILES, int EPI>
__global__ __launch_bounds__(256) void gemm_kernel(
    const u16* __restrict__ A, const u16* __restrict__ Bw, const float* __restrict__ bias,
    u16* __restrict__ o_q, u16* __restrict__ o_k, u16* __restrict__ o_v,
    float* __restrict__ o_f) {
    __shared__ u16 Asl[3][128 * 32];
    __shared__ u16 Bsl[3][128 * 32];

    const int wg = xcd_swizzle(blockIdx.x, gridDim.x);
    const int tm = wg / NTILES, tn = wg % NTILES;
    const int tid = threadIdx.x, wave = tid >> 6, lane = tid & 63;
    const int l15 = lane & 15, l4 = lane >> 4;
    const int wm = (wave >> 1) * 64, wn = (wave & 1) * 64;

    const u16* Ab = A + (size_t)tm * 128 * KDIM;
    const u16* Bb = Bw + (size_t)tn * 128 * KDIM;

    f32x4 acc[4][4] = {};

    auto stage = [&](int buf, int k0) {
#pragma unroll
        for (int i = 0; i < 2; i++) {
            int row = wave * 32 + i * 16 + (lane >> 2);
            int sc = (lane & 3) ^ ((row >> 1) & 3);
            gload_lds16(Ab + (size_t)row * KDIM + k0 + sc * 8,
                        &Asl[buf][(wave * 32 + i * 16) * 32]);
            gload_lds16(Bb + (size_t)row * KDIM + k0 + sc * 8,
                        &Bsl[buf][(wave * 32 + i * 16) * 32]);
        }
    };

    constexpr int NT = KDIM / 32;
    stage(0, 0);
    stage(1, 32);
#pragma unroll
    for (int t = 0; t < NT; ++t) {
        if (t + 2 < NT) {
            stage((t + 2) % 3, (t + 2) * 32);
            asm volatile("s_waitcnt vmcnt(8)" ::: "memory");  // tile t landed; t+1,t+2 in flight
        } else if (t + 1 < NT) {
            asm volatile("s_waitcnt vmcnt(4)" ::: "memory");
        } else {
            asm volatile("s_waitcnt vmcnt(0)" ::: "memory");
        }
        __builtin_amdgcn_s_barrier();

        const char* As = (const char*)Asl[t % 3];
        const char* Bs = (const char*)Bsl[t % 3];
        short8 af[4], bfr[4];
#pragma unroll
        for (int u = 0; u < 4; u++) {
            int rowa = wm + u * 16 + l15;
            int bytea = rowa * 64 + ((l4 * 16) ^ (((rowa >> 1) & 3) << 4));
            af[u] = *reinterpret_cast<const short8*>(As + bytea);
            int rowb = wn + u * 16 + l15;
            int byteb = rowb * 64 + ((l4 * 16) ^ (((rowb >> 1) & 3) << 4));
            bfr[u] = *reinterpret_cast<const short8*>(Bs + byteb);
        }
        __builtin_amdgcn_s_setprio(1);
#pragma unroll
        for (int mt = 0; mt < 4; mt++)
#pragma unroll
            for (int nt = 0; nt < 4; nt++)
                acc[mt][nt] = mfma16(af[mt], bfr[nt], acc[mt][nt]);
        __builtin_amdgcn_s_setprio(0);
        __builtin_amdgcn_s_barrier();
    }

    // epilogue (all stores coalesced over l15)
#pragma unroll
    for (int mt = 0; mt < 4; mt++) {
#pragma unroll
        for (int nt = 0; nt < 4; nt++) {
            int gn = tn * 128 + wn + nt * 16 + l15;
            float bv = bias[gn];
#pragma unroll
            for (int r = 0; r < 4; r++) {
                int gm = tm * 128 + wm + mt * 16 + l4 * 4 + r;  // chunk-local token row
                float v = acc[mt][nt][r] + bv;
                if (EPI == 0) {
                    int bb = gm / 196, nn = gm - bb * 196;
                    int h = gn / 192, r2 = gn - h * 192;
                    int bh = bb * 8 + h;
                    if (r2 < 32)
                        o_q[((size_t)bh * 196 + nn) * 32 + r2] = f2b(v);
                    else if (r2 < 64)
                        o_k[((size_t)bh * 196 + nn) * 32 + (r2 - 32)] = f2b(v);
                    else
                        o_v[((size_t)bh * 196 + nn) * 128 + (r2 - 64)] = f2b(v);
                } else {
                    o_f[(size_t)gm * 384 + gn] = v;
                }
            }
        }
    }
}

// ---------------- fused attention per chunk-local (b,h), 8 waves ----------------
// Swapped QK^T (mfma(K,Q)) -> lane holds P[q=i0+l15][k=jt*16+l4*4+r]: softmax is
// in-lane + 2 shfl; P redistributed to PV A-fragments via pack + DOUBLE shfl.
// CRITICAL: the outer tile loop must NOT be unrolled (#pragma unroll 1) — its
// trip count is <=2 and unrolling doubles the live register arrays
// (2x s[13] + 2x pk + o = ~220 VGPR) forcing a massive scratch spill
// (r9/r10 PMC: 128-VGPR cap, ~260 MB/dispatch scratch traffic, 97 us).
// One iteration's live set is ~110 VGPR — fits with zero spill.
__global__ __launch_bounds__(512, 1) void attn_kernel(
    const u16* __restrict__ qb, const u16* __restrict__ kb, const u16* __restrict__ vb,
    const float* __restrict__ bm, u16* __restrict__ out) {
    __shared__ u16 Klds[224 * 40];   // padded stride 40
    __shared__ u16 Vlds[128 * 232];  // V^T: rows d, cols k (padded 232)

    const int bh = blockIdx.x;  // chunk-local
    const int b = bh >> 3, h = bh & 7;
    const int tid = threadIdx.x, wave = tid >> 6, lane = tid & 63;
    const int l15 = lane & 15, l4 = lane >> 4;

    // zero only Vlds cols 196..223 (PV reads there with P=0; keep finite)
    for (int u = tid; u < 128 * 28; u += 512) {
        int rw = u / 28, c = u - rw * 28;
        Vlds[rw * 232 + 196 + c] = 0;
    }
    // stage K (zero-fill rows >= 196)
    const u16* kbase = kb + (size_t)bh * (196 * 32);
    for (int u = tid; u < 896; u += 512) {
        int j = u >> 2, c8 = (u & 3) * 8;
        short8 v = {};
        if (j < 196) v = *reinterpret_cast<const short8*>(kbase + j * 32 + c8);
        *reinterpret_cast<short8*>(&Klds[j * 40 + c8]) = v;
    }
    // transposed V stage with staggered-diagonal write order (r6)
    const u16* vbase = vb + (size_t)bh * (196 * 128);
    for (int u0 = tid; u0 < 3136; u0 += 512) {  // 3136 = 196*128/8
        int k = u0 >> 4;
        int d0 = (u0 & 15) * 8;
        short8 vv = *reinterpret_cast<const short8*>(vbase + k * 128 + d0);
#pragma unroll
        for (int jj = 0; jj < 8; jj++) {
            int j = (jj + lane) & 7;
            Vlds[(d0 + j) * 232 + k] = (u16)vv[j];
        }
    }
    __syncthreads();

    const float* bmh = bm + h * (196 * 196);
    const u16* qbase = qb + (size_t)bh * (196 * 32);

#pragma unroll 1
    for (int it = wave; it < 13; it += 8) {
        int i0 = it * 16;
        int q = i0 + l15;
        int qcl = q < 196 ? q : 195;
        short8 qf = *reinterpret_cast<const short8*>(qbase + qcl * 32 + l4 * 8);  // B operand

        // QK^T swapped: s[jt][r] = S[k=jt*16+l4*4+r][q=i0+l15]
        f32x4 s[13];
        __builtin_amdgcn_s_setprio(1);
#pragma unroll
        for (int jt = 0; jt < 13; jt++) {
            short8 kf = *reinterpret_cast<const short8*>(&Klds[(jt * 16 + l15) * 40 + l4 * 8]);
            f32x4 z = {0.f, 0.f, 0.f, 0.f};
            s[jt] = mfma16(kf, qf, z);
        }
        __builtin_amdgcn_s_setprio(0);

        // softmax over k: in-lane 52 + cross-l4 shfl(16,32); bias via symmetry
        float mx = -3e38f;
#pragma unroll
        for (int jt = 0; jt < 13; jt++) {
#pragma unroll
            for (int r = 0; r < 4; r++) {
                int gk = jt * 16 + l4 * 4 + r;
                float v = (gk < 196) ? (s[jt][r] * SCALE_QK + bmh[gk * 196 + qcl]) : -3e38f;
                s[jt][r] = v;
                mx = fmaxf(mx, v);
            }
        }
        mx = fmaxf(mx, __shfl_xor(mx, 16));
        mx = fmaxf(mx, __shfl_xor(mx, 32));
        float sum = 0.f;
#pragma unroll
        for (int jt = 0; jt < 13; jt++) {
#pragma unroll
            for (int r = 0; r < 4; r++) {
                float p = __expf(s[jt][r] - mx);
                s[jt][r] = p;
                sum += p;
            }
        }
        sum += __shfl_xor(sum, 16);
        sum += __shfl_xor(sum, 32);
        float inv = 1.f / sum;

        // normalize + pack to bf16 pairs: pk01=(r0,r1), pk23=(r2,r3) per jt
        u32 pk01[14], pk23[14];
#pragma unroll
        for (int jt = 0; jt < 13; jt++) {
            pk01[jt] = pack2(s[jt][0] * inv, s[jt][1] * inv);
            pk23[jt] = pack2(s[jt][2] * inv, s[jt][3] * inv);
        }
        pk01[13] = 0; pk23[13] = 0;  // k in [208,224): P = 0

        // PV: rebuild A-fragment (row=q=l15, k=ks*32+l4*8+e). For dest word w:
        //   jt = ks*2 + (l4_dest>>1)   [DESTINATION-selected!]
        //   rpair = w&1  (pk01 / pk23)
        //   source lane = l15 + 16*((l4_dest&1)*2 + (w>>1))
        // One shfl cannot carry both jt candidates (same source serves both),
        // so shfl both and select on the destination's l4>>1.
        f32x4 o[8] = {};
        const int sl0 = l15 + ((l4 & 1) * 2) * 16;  // for words 0,1
        const int sl1 = sl0 + 16;                   // for words 2,3
        const bool hi_jt = (l4 & 2) != 0;           // destination l4>>1
#pragma unroll
        for (int ks = 0; ks < 7; ks++) {
            u32 a0 = __shfl(pk01[ks * 2], sl0), a1 = __shfl(pk01[ks * 2 + 1], sl0);
            u32 b0 = __shfl(pk23[ks * 2], sl0), b1 = __shfl(pk23[ks * 2 + 1], sl0);
            u32 c0 = __shfl(pk01[ks * 2], sl1), c1 = __shfl(pk01[ks * 2 + 1], sl1);
            u32 d0_ = __shfl(pk23[ks * 2], sl1), d1 = __shfl(pk23[ks * 2 + 1], sl1);
            u32x4 pw;
            pw.x = hi_jt ? a1 : a0;
            pw.y = hi_jt ? b1 : b0;
            pw.z = hi_jt ? c1 : c0;
            pw.w = hi_jt ? d1 : d0_;
            short8 pa = __builtin_bit_cast(short8, pw);
            __builtin_amdgcn_s_setprio(1);
#pragma unroll
            for (int dt = 0; dt < 8; dt++) {
                short8 vf = *reinterpret_cast<const short8*>(
                    &Vlds[(dt * 16 + l15) * 232 + ks * 32 + l4 * 8]);
                o[dt] = mfma16(pa, vf, o[dt]);
            }
            __builtin_amdgcn_s_setprio(0);
        }

        // store O as bf16 into chunk-local [token][h*128+d]
        u16* ob = out + ((size_t)b * 196) * 1024 + h * 128;
#pragma unroll
        for (int dt = 0; dt < 8; dt++) {
#pragma unroll
            for (int r = 0; r < 4; r++) {
                int gi = i0 + l4 * 4 + r;
                if (gi < 196) ob[(size_t)gi * 1024 + dt * 16 + l15] = f2b(o[dt][r]);
            }
        }
    }
}

extern "C" void kernel_launch(void* const* d_in, const int* in_sizes, int n_in,
                              void* d_out, int out_size, void* d_ws, size_t ws_size,
                              hipStream_t stream) {
    const float* x = (const float*)d_in[0];
    const float* w_qkv = (const float*)d_in[1];
    const float* b_qkv = (const float*)d_in[2];
    const float* w_proj = (const float*)d_in[3];
    const float* b_proj = (const float*)d_in[4];
    const float* attn_biases = (const float*)d_in[5];
    const int* bias_idxs = (const int*)d_in[6];
    float* out = (float*)d_out;

    // runtime workspace plan (ws_size fixed across calls -> deterministic)
    const size_t MB = 1ull << 20;
    int nc;
    bool full_aout;
    if (ws_size >= 310 * MB)      { nc = 1; full_aout = true; }
    else if (ws_size >= 165 * MB) { nc = 4; full_aout = true; }
    else                          { nc = 4; full_aout = false; }
    const int cb = 256 / nc;
    const size_t chm = (size_t)cb * 196;
    const int chbh = cb * 8;

    char* p = (char*)d_ws;
    auto alloc = [&](size_t bytes) {
        void* r = (void*)p;
        p += (bytes + 255) & ~(size_t)255;
        return r;
    };
    // persistent (~3.2 MB)
    u16* wqb = (u16*)alloc(1536ull * 384 * 2);
    u16* wpb = (u16*)alloc(384ull * 1024 * 2);
    float* bmat = (float*)alloc(8ull * 196 * 196 * 4);
    // chunk buffers
    u16* xbc = (u16*)alloc(chm * 384 * 2);
    u16* qc = (u16*)alloc((size_t)chbh * 196 * 32 * 2);
    u16* kc = (u16*)alloc((size_t)chbh * 196 * 32 * 2);
    u16* vc = (u16*)alloc((size_t)chbh * 196 * 128 * 2);
    u16* aout_b = (u16*)alloc((full_aout ? 50176ull : chm) * 1024 * 2);

    // one-time prep
    cvt_kernel<<<576, 256, 0, stream>>>((const float4*)w_qkv, (ushort4*)wqb, 1536 * 384 / 4);
    cvt_kernel<<<384, 256, 0, stream>>>((const float4*)w_proj, (ushort4*)wpb, 384 * 1024 / 4);
    biasmat_kernel<<<1201, 256, 0, stream>>>(attn_biases, bias_idxs, bmat);

    const int qkv_grid = (int)(chm / 128) * 12;
    const int proj_grid_chunk = (int)(chm / 128) * 3;

    for (int c = 0; c < nc; ++c) {
        const float* xc = x + (size_t)c * chm * 384;
        cvt_kernel<<<1024, 256, 0, stream>>>((const float4*)xc, (ushort4*)xbc,
                                             (int)(chm * 384 / 4));
        gemm_kernel<384, 12, 0><<<qkv_grid, 256, 0, stream>>>(xbc, wqb, b_qkv, qc, kc, vc,
                                                              nullptr);
        u16* aoutc = aout_b + (full_aout ? (size_t)c * chm * 1024 : 0);
        attn_kernel<<<chbh, 512, 0, stream>>>(qc, kc, vc, bmat, aoutc);
        if (!full_aout) {
            gemm_kernel<1024, 3, 1><<<proj_grid_chunk, 256, 0, stream>>>(
                aoutc, wpb, b_proj, nullptr, nullptr, nullptr, out + (size_t)c * chm * 384);
        }
    }
    if (full_aout) {
        gemm_kernel<1024, 3, 1><<<392 * 3, 256, 0, stream>>>(aout_b, wpb, b_proj, nullptr,
                                                             nullptr, nullptr, out);
    }
}

// Round 14
// 382.291 us; speedup vs baseline: 1.6409x; 1.6409x over previous
//
#include <hip/hip_runtime.h>

typedef unsigned short u16;
typedef unsigned int u32;
typedef short short8 __attribute__((ext_vector_type(8)));
typedef float f32x4 __attribute__((ext_vector_type(4)));
typedef __bf16 bf16x8 __attribute__((ext_vector_type(8)));
typedef unsigned int u32x4 __attribute__((ext_vector_type(4)));

#define SCALE_QK 0.17677669529663687f  // 1/sqrt(32)

__device__ __forceinline__ u16 f2b(float f) {
    unsigned int u = __builtin_bit_cast(unsigned int, f);
    u += 0x7fffu + ((u >> 16) & 1u);
    return (u16)(u >> 16);
}

__device__ __forceinline__ u32 pack2(float lo, float hi) {
    return ((u32)f2b(hi) << 16) | (u32)f2b(lo);
}

__device__ __forceinline__ f32x4 mfma16(short8 a, short8 b, f32x4 c) {
    return __builtin_amdgcn_mfma_f32_16x16x32_bf16(
        __builtin_bit_cast(bf16x8, a), __builtin_bit_cast(bf16x8, b), c, 0, 0, 0);
}

__device__ __forceinline__ void gload_lds16(const u16* g, u16* l) {
    __builtin_amdgcn_global_load_lds(
        (const __attribute__((address_space(1))) unsigned int*)g,
        (__attribute__((address_space(3))) unsigned int*)l, 16, 0, 0);
}

// bijective XCD-chunked block-id swizzle (m204)
__device__ __forceinline__ int xcd_swizzle(int bid, int nwg) {
    int qd = nwg >> 3, rm = nwg & 7;
    int xcd = bid & 7, lo = bid >> 3;
    return (xcd < rm ? xcd * (qd + 1) : rm * (qd + 1) + (xcd - rm) * qd) + lo;
}

// ---------------- fp32 -> bf16 convert ----------------
__global__ void cvt_kernel(const float4* __restrict__ in, ushort4* __restrict__ out, int n4) {
    int stride = gridDim.x * blockDim.x;
    for (int i = blockIdx.x * blockDim.x + threadIdx.x; i < n4; i += stride) {
        float4 v = in[i];
        ushort4 o;
        o.x = f2b(v.x); o.y = f2b(v.y); o.z = f2b(v.z); o.w = f2b(v.w);
        out[i] = o;
    }
}

// ---------------- bias matrix expand: bm[h][i][j] = ab[h][idx[i][j]] ----------------
// (idx is symmetric -> bm[h] is symmetric; attn reads bm[k][q] relying on this)
__global__ void biasmat_kernel(const float* __restrict__ ab, const int* __restrict__ idxs,
                               float* __restrict__ bm) {
    int total = 8 * 196 * 196;
    int stride = gridDim.x * blockDim.x;
    for (int i = blockIdx.x * blockDim.x + threadIdx.x; i < total; i += stride) {
        int h = i / (196 * 196);
        int ij = i - h * (196 * 196);
        bm[i] = ab[h * 196 + idxs[ij]];
    }
}

// ---------------- bf16 GEMM: C = A(M x K) * Bw(N x K)^T + bias ----------------
// 128x128 tile, 4 waves (64x64 each), BK=32, THREE LDS buffers with 2-deep
// counted-vmcnt prefetch (stage t+2 during compute t; vmcnt(8) retires tile t).
// Bank swizzle: slot ^= (row>>1)&3 -> balanced bank quads (conflict-free, r6 PMC).
// EPI==0: route outputs to q/k/v (qkv, chunk-local).  EPI==1: fp32 out (proj).
template <int KDIM, int NTILES, int EPI>
__global__ __launch_bounds__(256) void gemm_kernel(
    const u16* __restrict__ A, const u16* __restrict__ Bw, const float* __restrict__ bias,
    u16* __restrict__ o_q, u16* __restrict__ o_k, u16* __restrict__ o_v,
    float* __restrict__ o_f) {
    __shared__ u16 Asl[3][128 * 32];
    __shared__ u16 Bsl[3][128 * 32];

    const int wg = xcd_swizzle(blockIdx.x, gridDim.x);
    const int tm = wg / NTILES, tn = wg % NTILES;
    const int tid = threadIdx.x, wave = tid >> 6, lane = tid & 63;
    const int l15 = lane & 15, l4 = lane >> 4;
    const int wm = (wave >> 1) * 64, wn = (wave & 1) * 64;

    const u16* Ab = A + (size_t)tm * 128 * KDIM;
    const u16* Bb = Bw + (size_t)tn * 128 * KDIM;

    f32x4 acc[4][4] = {};

    auto stage = [&](int buf, int k0) {
#pragma unroll
        for (int i = 0; i < 2; i++) {
            int row = wave * 32 + i * 16 + (lane >> 2);
            int sc = (lane & 3) ^ ((row >> 1) & 3);
            gload_lds16(Ab + (size_t)row * KDIM + k0 + sc * 8,
                        &Asl[buf][(wave * 32 + i * 16) * 32]);
            gload_lds16(Bb + (size_t)row * KDIM + k0 + sc * 8,
                        &Bsl[buf][(wave * 32 + i * 16) * 32]);
        }
    };

    constexpr int NT = KDIM / 32;
    stage(0, 0);
    stage(1, 32);
#pragma unroll
    for (int t = 0; t < NT; ++t) {
        if (t + 2 < NT) {
            stage((t + 2) % 3, (t + 2) * 32);
            asm volatile("s_waitcnt vmcnt(8)" ::: "memory");  // tile t landed; t+1,t+2 in flight
        } else if (t + 1 < NT) {
            asm volatile("s_waitcnt vmcnt(4)" ::: "memory");
        } else {
            asm volatile("s_waitcnt vmcnt(0)" ::: "memory");
        }
        __builtin_amdgcn_s_barrier();

        const char* As = (const char*)Asl[t % 3];
        const char* Bs = (const char*)Bsl[t % 3];
        short8 af[4], bfr[4];
#pragma unroll
        for (int u = 0; u < 4; u++) {
            int rowa = wm + u * 16 + l15;
            int bytea = rowa * 64 + ((l4 * 16) ^ (((rowa >> 1) & 3) << 4));
            af[u] = *reinterpret_cast<const short8*>(As + bytea);
            int rowb = wn + u * 16 + l15;
            int byteb = rowb * 64 + ((l4 * 16) ^ (((rowb >> 1) & 3) << 4));
            bfr[u] = *reinterpret_cast<const short8*>(Bs + byteb);
        }
        __builtin_amdgcn_s_setprio(1);
#pragma unroll
        for (int mt = 0; mt < 4; mt++)
#pragma unroll
            for (int nt = 0; nt < 4; nt++)
                acc[mt][nt] = mfma16(af[mt], bfr[nt], acc[mt][nt]);
        __builtin_amdgcn_s_setprio(0);
        __builtin_amdgcn_s_barrier();
    }

    // epilogue (all stores coalesced over l15)
#pragma unroll
    for (int mt = 0; mt < 4; mt++) {
#pragma unroll
        for (int nt = 0; nt < 4; nt++) {
            int gn = tn * 128 + wn + nt * 16 + l15;
            float bv = bias[gn];
#pragma unroll
            for (int r = 0; r < 4; r++) {
                int gm = tm * 128 + wm + mt * 16 + l4 * 4 + r;  // chunk-local token row
                float v = acc[mt][nt][r] + bv;
                if (EPI == 0) {
                    int bb = gm / 196, nn = gm - bb * 196;
                    int h = gn / 192, r2 = gn - h * 192;
                    int bh = bb * 8 + h;
                    if (r2 < 32)
                        o_q[((size_t)bh * 196 + nn) * 32 + r2] = f2b(v);
                    else if (r2 < 64)
                        o_k[((size_t)bh * 196 + nn) * 32 + (r2 - 32)] = f2b(v);
                    else
                        o_v[((size_t)bh * 196 + nn) * 128 + (r2 - 64)] = f2b(v);
                } else {
                    o_f[(size_t)gm * 384 + gn] = v;
                }
            }
        }
    }
}

// ---------------- fused attention per chunk-local (b,h), 8 waves ----------------
// Swapped QK^T (mfma(K,Q)) -> lane holds P[q=i0+l15][k=jt*16+l4*4+r]; in-lane
// softmax; P redistributed to PV A-fragments via pack + double shfl; no P LDS.
// Deferred normalization NOTE (r12 bug): after the PV MFMA, the lane's o[dt][r]
// belongs to D-row q = i0 + l4*4 + r, NOT q = i0 + l15 where inv was computed.
// inv is l4-uniform after the shfl_xor(16/32) reductions, so the correct
// normalizer lives in lane l4*4+r: invr[r] = __shfl(inv, l4*4+r).
__global__ __launch_bounds__(512, 1) void attn_kernel(
    const u16* __restrict__ qb, const u16* __restrict__ kb, const u16* __restrict__ vb,
    const float* __restrict__ bm, u16* __restrict__ out) {
    __shared__ u16 Klds[224 * 40];   // padded stride 40
    __shared__ u16 Vlds[128 * 232];  // V^T: rows d, cols k (padded 232)

    const int bh = blockIdx.x;  // chunk-local
    const int b = bh >> 3, h = bh & 7;
    const int tid = threadIdx.x, wave = tid >> 6, lane = tid & 63;
    const int l15 = lane & 15, l4 = lane >> 4;

    // zero only Vlds cols 196..223 (PV reads there with P=0; keep finite)
    for (int u = tid; u < 128 * 28; u += 512) {
        int rw = u / 28, c = u - rw * 28;
        Vlds[rw * 232 + 196 + c] = 0;
    }
    // stage K (zero-fill rows >= 196)
    const u16* kbase = kb + (size_t)bh * (196 * 32);
    for (int u = tid; u < 896; u += 512) {
        int j = u >> 2, c8 = (u & 3) * 8;
        short8 v = {};
        if (j < 196) v = *reinterpret_cast<const short8*>(kbase + j * 32 + c8);
        *reinterpret_cast<short8*>(&Klds[j * 40 + c8]) = v;
    }
    // transposed V stage, staggered-diagonal write order (r6) with STATIC vector
    // indices: rotate t left by (lane&7) via 3 conditional static rotations so
    // t[jj] == vv[(jj+lane)&7]; runtime index only in the ds_write address.
    const u16* vbase = vb + (size_t)bh * (196 * 128);
    for (int u0 = tid; u0 < 3136; u0 += 512) {  // 3136 = 196*128/8
        int k = u0 >> 4;
        int d0 = (u0 & 15) * 8;
        short8 t = *reinterpret_cast<const short8*>(vbase + k * 128 + d0);
#pragma unroll
        for (int bb_ = 0; bb_ < 3; bb_++) {
            int sh = 1 << bb_;
            bool doit = (lane >> bb_) & 1;
            short8 rr;
#pragma unroll
            for (int i = 0; i < 8; i++) rr[i] = t[(i + sh) & 7];
#pragma unroll
            for (int i = 0; i < 8; i++) t[i] = doit ? rr[i] : t[i];
        }
#pragma unroll
        for (int jj = 0; jj < 8; jj++) {
            int j = (jj + lane) & 7;
            Vlds[(d0 + j) * 232 + k] = (u16)t[jj];
        }
    }
    __syncthreads();

    const float* bmh = bm + h * (196 * 196);
    const u16* qbase = qb + (size_t)bh * (196 * 32);
    u16* ob = out + ((size_t)b * 196) * 1024 + h * 128;

    auto tile = [&](int it) {
        int i0 = it * 16;
        int q = i0 + l15;
        int qcl = q < 196 ? q : 195;
        short8 qf = *reinterpret_cast<const short8*>(qbase + qcl * 32 + l4 * 8);  // B operand

        // QK^T swapped: s[jt][r] = S[k=jt*16+l4*4+r][q=i0+l15]
        f32x4 s[13];
        __builtin_amdgcn_s_setprio(1);
#pragma unroll
        for (int jt = 0; jt < 13; jt++) {
            short8 kf = *reinterpret_cast<const short8*>(&Klds[(jt * 16 + l15) * 40 + l4 * 8]);
            f32x4 z = {0.f, 0.f, 0.f, 0.f};
            s[jt] = mfma16(kf, qf, z);
        }
        __builtin_amdgcn_s_setprio(0);

        // pass 1: scale + bias (symmetric: bm[k][q]), running max
        float mx = -3e38f;
#pragma unroll
        for (int jt = 0; jt < 13; jt++) {
#pragma unroll
            for (int r = 0; r < 4; r++) {
                int gk = jt * 16 + l4 * 4 + r;
                float v = (gk < 196) ? (s[jt][r] * SCALE_QK + bmh[gk * 196 + qcl]) : -3e38f;
                s[jt][r] = v;
                mx = fmaxf(mx, v);
            }
        }
        mx = fmaxf(mx, __shfl_xor(mx, 16));
        mx = fmaxf(mx, __shfl_xor(mx, 32));

        // pass 2: exp + pack (UNNORMALIZED; s dies per-element), running sum
        u32 pk01[14], pk23[14];
        float sum = 0.f;
#pragma unroll
        for (int jt = 0; jt < 13; jt++) {
            float p0 = __expf(s[jt][0] - mx);
            float p1 = __expf(s[jt][1] - mx);
            float p2 = __expf(s[jt][2] - mx);
            float p3 = __expf(s[jt][3] - mx);
            sum += (p0 + p1) + (p2 + p3);
            pk01[jt] = pack2(p0, p1);
            pk23[jt] = pack2(p2, p3);
        }
        pk01[13] = 0; pk23[13] = 0;  // k in [208,224): P = 0
        sum += __shfl_xor(sum, 16);
        sum += __shfl_xor(sum, 32);
        float inv = 1.f / sum;  // normalizer for q = i0 + l15 (this lane's softmax row)

        // fetch the normalizer for this lane's OUTPUT rows q = i0 + l4*4 + r:
        // it lives in lane l4*4+r (l15 == l4*4+r, l4-uniform after reductions).
        float invr[4];
#pragma unroll
        for (int r = 0; r < 4; r++) invr[r] = __shfl(inv, l4 * 4 + r);

        // PV: rebuild A-fragment (row=q=l15, k=ks*32+l4*8+e). For dest word w:
        //   jt = ks*2 + (l4_dest>>1), rpair = w&1, src lane = l15+16*((l4&1)*2+(w>>1)).
        // shfl both jt candidates; select on the destination's l4>>1.
        f32x4 o[8] = {};
        const int sl0 = l15 + ((l4 & 1) * 2) * 16;  // for words 0,1
        const int sl1 = sl0 + 16;                   // for words 2,3
        const bool hi_jt = (l4 & 2) != 0;           // destination l4>>1
#pragma unroll
        for (int ks = 0; ks < 7; ks++) {
            u32 a0 = __shfl(pk01[ks * 2], sl0), a1 = __shfl(pk01[ks * 2 + 1], sl0);
            u32 b0 = __shfl(pk23[ks * 2], sl0), b1 = __shfl(pk23[ks * 2 + 1], sl0);
            u32 c0 = __shfl(pk01[ks * 2], sl1), c1 = __shfl(pk01[ks * 2 + 1], sl1);
            u32 d0_ = __shfl(pk23[ks * 2], sl1), d1 = __shfl(pk23[ks * 2 + 1], sl1);
            u32x4 pw;
            pw.x = hi_jt ? a1 : a0;
            pw.y = hi_jt ? b1 : b0;
            pw.z = hi_jt ? c1 : c0;
            pw.w = hi_jt ? d1 : d0_;
            short8 pa = __builtin_bit_cast(short8, pw);
            __builtin_amdgcn_s_setprio(1);
#pragma unroll
            for (int dt = 0; dt < 8; dt++) {
                short8 vf = *reinterpret_cast<const short8*>(
                    &Vlds[(dt * 16 + l15) * 232 + ks * 32 + l4 * 8]);
                o[dt] = mfma16(pa, vf, o[dt]);
            }
            __builtin_amdgcn_s_setprio(0);
        }

        // store O (normalized per OUTPUT row via invr[r]) into [token][h*128+d]
#pragma unroll
        for (int dt = 0; dt < 8; dt++) {
#pragma unroll
            for (int r = 0; r < 4; r++) {
                int gi = i0 + l4 * 4 + r;
                if (gi < 196) ob[(size_t)gi * 1024 + dt * 16 + l15] = f2b(o[dt][r] * invr[r]);
            }
        }
    };

    tile(wave);          // tiles 0..7
    __syncthreads();     // hard scheduling fence: tile-1 registers dead here
    if (wave < 5) tile(wave + 8);  // tiles 8..12
}

extern "C" void kernel_launch(void* const* d_in, const int* in_sizes, int n_in,
                              void* d_out, int out_size, void* d_ws, size_t ws_size,
                              hipStream_t stream) {
    const float* x = (const float*)d_in[0];
    const float* w_qkv = (const float*)d_in[1];
    const float* b_qkv = (const float*)d_in[2];
    const float* w_proj = (const float*)d_in[3];
    const float* b_proj = (const float*)d_in[4];
    const float* attn_biases = (const float*)d_in[5];
    const int* bias_idxs = (const int*)d_in[6];
    float* out = (float*)d_out;

    // runtime workspace plan (ws_size fixed across calls -> deterministic)
    const size_t MB = 1ull << 20;
    int nc;
    bool full_aout;
    if (ws_size >= 310 * MB)      { nc = 1; full_aout = true; }
    else if (ws_size >= 165 * MB) { nc = 4; full_aout = true; }
    else                          { nc = 4; full_aout = false; }
    const int cb = 256 / nc;
    const size_t chm = (size_t)cb * 196;
    const int chbh = cb * 8;

    char* p = (char*)d_ws;
    auto alloc = [&](size_t bytes) {
        void* r = (void*)p;
        p += (bytes + 255) & ~(size_t)255;
        return r;
    };
    // persistent (~3.2 MB)
    u16* wqb = (u16*)alloc(1536ull * 384 * 2);
    u16* wpb = (u16*)alloc(384ull * 1024 * 2);
    float* bmat = (float*)alloc(8ull * 196 * 196 * 4);
    // chunk buffers
    u16* xbc = (u16*)alloc(chm * 384 * 2);
    u16* qc = (u16*)alloc((size_t)chbh * 196 * 32 * 2);
    u16* kc = (u16*)alloc((size_t)chbh * 196 * 32 * 2);
    u16* vc = (u16*)alloc((size_t)chbh * 196 * 128 * 2);
    u16* aout_b = (u16*)alloc((full_aout ? 50176ull : chm) * 1024 * 2);

    // one-time prep
    cvt_kernel<<<576, 256, 0, stream>>>((const float4*)w_qkv, (ushort4*)wqb, 1536 * 384 / 4);
    cvt_kernel<<<384, 256, 0, stream>>>((const float4*)w_proj, (ushort4*)wpb, 384 * 1024 / 4);
    biasmat_kernel<<<1201, 256, 0, stream>>>(attn_biases, bias_idxs, bmat);

    const int qkv_grid = (int)(chm / 128) * 12;
    const int proj_grid_chunk = (int)(chm / 128) * 3;

    for (int c = 0; c < nc; ++c) {
        const float* xc = x + (size_t)c * chm * 384;
        cvt_kernel<<<1024, 256, 0, stream>>>((const float4*)xc, (ushort4*)xbc,
                                             (int)(chm * 384 / 4));
        gemm_kernel<384, 12, 0><<<qkv_grid, 256, 0, stream>>>(xbc, wqb, b_qkv, qc, kc, vc,
                                                              nullptr);
        u16* aoutc = aout_b + (full_aout ? (size_t)c * chm * 1024 : 0);
        attn_kernel<<<chbh, 512, 0, stream>>>(qc, kc, vc, bmat, aoutc);
        if (!full_aout) {
            gemm_kernel<1024, 3, 1><<<proj_grid_chunk, 256, 0, stream>>>(
                aoutc, wpb, b_proj, nullptr, nullptr, nullptr, out + (size_t)c * chm * 384);
        }
    }
    if (full_aout) {
        gemm_kernel<1024, 3, 1><<<392 * 3, 256, 0, stream>>>(aout_b, wpb, b_proj, nullptr,
                                                             nullptr, nullptr, out);
    }
}